// Round 1
// baseline (1178.211 us; speedup 1.0000x reference)
//
#include <hip/hip_runtime.h>
#include <math.h>

#define BB   16
#define TT   1026
#define DD   64
#define HID  64
#define LEN  1024
#define NTOT (BB*LEN)   // 16384
#define TILE 256

__global__ void zero_out1(float* __restrict__ out1) {
    int i = blockIdx.x * 256 + threadIdx.x;
    if (i < NTOT) out1[i] = 0.0f;
}

__global__ __launch_bounds__(256, 2)
void np_prior_kernel(const float* __restrict__ x,  const float* __restrict__ W1,
                     const float* __restrict__ b1, const float* __restrict__ W2,
                     const float* __restrict__ b2, const float* __restrict__ W3,
                     const float* __restrict__ b3, float* __restrict__ out)
{
    // Transposed weight tiles: broadcast (uniform-address) LDS reads -> no bank conflicts
    __shared__ float sW1[128 * 64];  // [f][h] = W1[l][h][f], f<128
    __shared__ float sW2[64 * 64];   // [h][g] = W2[l][g][h]
    __shared__ float sW1L[64];       // w1_last[h] = W1[l][h][128]
    __shared__ float sB1[64], sB2[64], sW3[64];

    const int l   = blockIdx.x;
    const int tid = threadIdx.x;

    for (int e = tid; e < 64 * 129; e += 256) {
        int h = e / 129, f = e - h * 129;
        float v = W1[(l * 64 + h) * 129 + f];
        if (f < 128) sW1[f * 64 + h] = v;
        else         sW1L[h] = v;
    }
    for (int e = tid; e < 64 * 64; e += 256) {
        int g = e >> 6, h = e & 63;
        sW2[h * 64 + g] = W2[(l * 64 + g) * 64 + h];
    }
    if (tid < 64) {
        sB1[tid] = b1[l * 64 + tid];
        sB2[tid] = b2[l * 64 + tid];
        sW3[tid] = W3[l * 64 + tid];   // W3[l][0][g]
    }
    __syncthreads();

    const int n  = blockIdx.y * TILE + tid;     // grid exact: n < 16384
    const int bb = n >> 10;
    const int t  = n & 1023;
    const float* xrow = x + ((size_t)(bb * TT + t)) * DD;  // xrow[0..127] = lags, xrow[128+l] = x_t[l]

    // ---- stage 1: z1[h] = b1 + sum_f x_lags[f]*W1[h][f] + x_t*w1_last[h]
    float z1[64];
    #pragma unroll
    for (int h = 0; h < 64; ++h) z1[h] = sB1[h];

    const float4* xv4 = (const float4*)xrow;   // 16B-aligned: row offset multiple of 64 floats
    #pragma unroll 2
    for (int f4 = 0; f4 < 32; ++f4) {
        float4 xv = xv4[f4];
        float xs[4] = {xv.x, xv.y, xv.z, xv.w};
        #pragma unroll
        for (int c = 0; c < 4; ++c) {
            float xf = xs[c];
            const float4* w = (const float4*)(sW1 + (f4 * 4 + c) * 64);
            #pragma unroll
            for (int q = 0; q < 16; ++q) {
                float4 wv = w[q];
                z1[4*q+0] += xf * wv.x;  z1[4*q+1] += xf * wv.y;
                z1[4*q+2] += xf * wv.z;  z1[4*q+3] += xf * wv.w;
            }
        }
    }
    {
        float xt = xrow[2 * DD + l];
        #pragma unroll
        for (int h = 0; h < 64; ++h) z1[h] += xt * sW1L[h];
    }

    // ---- stage 2: z2a[g] = sum_h leaky(z1[h])*W2[g][h]; z2t[g] = sum_h dleaky(z1[h])*w1l[h]*W2[g][h]
    float z2a[64], z2t[64];
    #pragma unroll
    for (int g = 0; g < 64; ++g) { z2a[g] = 0.0f; z2t[g] = 0.0f; }

    #pragma unroll 2
    for (int h = 0; h < 64; ++h) {
        float z  = z1[h];
        float a1 = z > 0.0f ? z : 0.01f * z;
        float t1 = (z > 0.0f ? 1.0f : 0.01f) * sW1L[h];
        const float4* w = (const float4*)(sW2 + h * 64);
        #pragma unroll
        for (int q = 0; q < 16; ++q) {
            float4 wv = w[q];
            z2a[4*q+0] += a1 * wv.x;  z2t[4*q+0] += t1 * wv.x;
            z2a[4*q+1] += a1 * wv.y;  z2t[4*q+1] += t1 * wv.y;
            z2a[4*q+2] += a1 * wv.z;  z2t[4*q+2] += t1 * wv.z;
            z2a[4*q+3] += a1 * wv.w;  z2t[4*q+3] += t1 * wv.w;
        }
    }

    // ---- stage 3: out = sum_g leaky(z2+b2)*w3 + b3 ; dJ = sum_g dleaky(z2)*z2t*w3
    float o = 0.0f, dj = 0.0f;
    #pragma unroll
    for (int g = 0; g < 64; ++g) {
        float z  = z2a[g] + sB2[g];
        float a2 = z > 0.0f ? z : 0.01f * z;
        float d2 = z > 0.0f ? 1.0f : 0.01f;
        o  += a2 * sW3[g];
        dj += d2 * z2t[g] * sW3[g];
    }

    out[(size_t)n * 64 + l] = o + b3[l];                         // residuals[b][t][l]
    atomicAdd(out + (size_t)NTOT * 64 + n, __logf(fabsf(dj)));   // log_abs_det[b][t]
}

extern "C" void kernel_launch(void* const* d_in, const int* in_sizes, int n_in,
                              void* d_out, int out_size, void* d_ws, size_t ws_size,
                              hipStream_t stream) {
    const float* x  = (const float*)d_in[0];
    const float* W1 = (const float*)d_in[1];
    const float* b1 = (const float*)d_in[2];
    const float* W2 = (const float*)d_in[3];
    const float* b2 = (const float*)d_in[4];
    const float* W3 = (const float*)d_in[5];
    const float* b3 = (const float*)d_in[6];
    float* out = (float*)d_out;

    hipLaunchKernelGGL(zero_out1, dim3(NTOT / 256), dim3(256), 0, stream,
                       out + (size_t)NTOT * 64);

    dim3 grid(64 /*l*/, NTOT / TILE /*n tiles*/);
    hipLaunchKernelGGL(np_prior_kernel, grid, dim3(256), 0, stream,
                       x, W1, b1, W2, b2, W3, b3, out);
}

// Round 3
// 322.904 us; speedup vs baseline: 3.6488x; 3.6488x over previous
//
#include <hip/hip_runtime.h>
#include <math.h>

#define BB   16
#define TT   1026
#define LEN  1024
#define NTOT (BB*LEN)   // 16384
#define AST  68         // region A row stride (uints)
#define BST  68         // region B row stride (uints)

typedef __attribute__((ext_vector_type(8))) short bf16x8;
typedef __attribute__((ext_vector_type(4))) float f32x4;
typedef __attribute__((ext_vector_type(4))) unsigned int u32x4;

__device__ __forceinline__ unsigned int rne16(unsigned int u) {
    return (u + 0x7FFFu + ((u >> 16) & 1u)) >> 16;
}
// pack v as (bf16_hi << 16) | bf16_lo, where hi = rne(v), lo = rne(v - hi)
__device__ __forceinline__ unsigned int packbf(float v) {
    unsigned int u  = __float_as_uint(v);
    unsigned int hi = rne16(u);
    float lof = v - __uint_as_float(hi << 16);
    unsigned int lo = rne16(__float_as_uint(lof));
    return (hi << 16) | (lo & 0xFFFFu);
}
// read 8 packed elements -> hi-frag and lo-frag (bf16x8 each)
__device__ __forceinline__ void loadfrag(const unsigned int* p, bf16x8* hi, bf16x8* lo) {
    u32x4 w0 = *(const u32x4*)p;
    u32x4 w1 = *(const u32x4*)(p + 4);
    union { unsigned int u[4]; bf16x8 v; } H, L;
    H.u[0] = __builtin_amdgcn_perm(w0[1], w0[0], 0x07060302u);
    H.u[1] = __builtin_amdgcn_perm(w0[3], w0[2], 0x07060302u);
    H.u[2] = __builtin_amdgcn_perm(w1[1], w1[0], 0x07060302u);
    H.u[3] = __builtin_amdgcn_perm(w1[3], w1[2], 0x07060302u);
    L.u[0] = __builtin_amdgcn_perm(w0[1], w0[0], 0x05040100u);
    L.u[1] = __builtin_amdgcn_perm(w0[3], w0[2], 0x05040100u);
    L.u[2] = __builtin_amdgcn_perm(w1[1], w1[0], 0x05040100u);
    L.u[3] = __builtin_amdgcn_perm(w1[3], w1[2], 0x05040100u);
    *hi = H.v; *lo = L.v;
}

__global__ void zero_logdet(float* __restrict__ p) {
    int i = blockIdx.x * 256 + threadIdx.x;
    if (i < NTOT) p[i] = 0.0f;
}

__global__ __launch_bounds__(256, 2)
void np_prior_mfma2(const float* __restrict__ x,  const float* __restrict__ W1,
                    const float* __restrict__ b1, const float* __restrict__ W2,
                    const float* __restrict__ b2, const float* __restrict__ W3,
                    const float* __restrict__ b3, float* __restrict__ out)
{
    __shared__ unsigned int uA[130 * AST];  // x (rows 0..129) -> a1 -> t1  (packed hi|lo)
    __shared__ unsigned int uB[64 * BST];   // W1 k-chunk -> W2             (packed hi|lo)
    __shared__ float sW1L[64], sB1[64], sB2[64], sW3[64];

    const int l = blockIdx.x, tid = threadIdx.x;
    const int n_base = blockIdx.y * 128;
    const int bb = n_base >> 10, t0 = n_base & 1023;
    const float* xbase = x  + (size_t)(bb * TT + t0) * 64;
    const float* W1l   = W1 + (size_t)l * 64 * 129;
    const float* W2l   = W2 + (size_t)l * 64 * 64;

    // ---- stage x and W1 chunk 0 ----
    for (int p = tid; p < 130 * 16; p += 256) {
        int r = p >> 4, c = (p & 15) * 4;
        float4 v = *(const float4*)(xbase + r * 64 + c);
        u32x4 pk = { packbf(v.x), packbf(v.y), packbf(v.z), packbf(v.w) };
        *(u32x4*)&uA[r * AST + c] = pk;
    }
    for (int e = tid; e < 1024; e += 256) {
        int h = e >> 4, f0 = (e & 15) * 4;
        const float* src = W1l + h * 129 + f0;             // chunk 0: f in [0,64)
        u32x4 pk = { packbf(src[0]), packbf(src[1]), packbf(src[2]), packbf(src[3]) };
        *(u32x4*)&uB[h * BST + f0] = pk;
    }
    if (tid < 64) {
        sW1L[tid] = W1l[tid * 129 + 128];
        sB1[tid]  = b1[l * 64 + tid];
        sB2[tid]  = b2[l * 64 + tid];
        sW3[tid]  = W3[l * 64 + tid];
    }
    __syncthreads();

    const int wid = tid >> 6, lane = tid & 63;
    const int q = lane >> 4, c16 = lane & 15;
    const int wrow = wid * 32;

    // ---- stage 1: z1 = x_lags @ W1' (K=128, two 64-chunks, 3-pass split bf16) ----
    f32x4 z1[2][4];
    #pragma unroll
    for (int mt = 0; mt < 2; ++mt)
        #pragma unroll
        for (int nt = 0; nt < 4; ++nt) z1[mt][nt] = (f32x4){0.f,0.f,0.f,0.f};

    #pragma unroll
    for (int chunk = 0; chunk < 2; ++chunk) {
        if (chunk == 1) {
            __syncthreads();   // chunk-0 frag reads done
            for (int e = tid; e < 1024; e += 256) {
                int h = e >> 4, f0 = (e & 15) * 4;
                const float* src = W1l + h * 129 + 64 + f0;    // chunk 1: f in [64,128)
                u32x4 pk = { packbf(src[0]), packbf(src[1]), packbf(src[2]), packbf(src[3]) };
                *(u32x4*)&uB[h * BST + f0] = pk;
            }
            __syncthreads();
        }
        #pragma unroll
        for (int kc2 = 0; kc2 < 2; ++kc2) {
            bf16x8 ah[2], al[2], bh[4], bl[4];
            #pragma unroll
            for (int mt = 0; mt < 2; ++mt)
                loadfrag(&uA[(wrow + mt * 16 + c16 + chunk) * AST + kc2 * 32 + q * 8], &ah[mt], &al[mt]);
            #pragma unroll
            for (int nt = 0; nt < 4; ++nt)
                loadfrag(&uB[(nt * 16 + c16) * BST + kc2 * 32 + q * 8], &bh[nt], &bl[nt]);
            #pragma unroll
            for (int mt = 0; mt < 2; ++mt)
                #pragma unroll
                for (int nt = 0; nt < 4; ++nt) {
                    z1[mt][nt] = __builtin_amdgcn_mfma_f32_16x16x32_bf16(ah[mt], bh[nt], z1[mt][nt], 0, 0, 0);
                    z1[mt][nt] = __builtin_amdgcn_mfma_f32_16x16x32_bf16(al[mt], bh[nt], z1[mt][nt], 0, 0, 0);
                    z1[mt][nt] = __builtin_amdgcn_mfma_f32_16x16x32_bf16(ah[mt], bl[nt], z1[mt][nt], 0, 0, 0);
                }
        }
    }

    // finalize z1 in fp32: + x_t*w1_last + b1   (x_t reconstructed hi+lo)
    float w1lc[4], b1c[4], b2c[4], w3c[4];
    #pragma unroll
    for (int nt = 0; nt < 4; ++nt) {
        w1lc[nt] = sW1L[nt * 16 + c16];
        b1c[nt]  = sB1 [nt * 16 + c16];
        b2c[nt]  = sB2 [nt * 16 + c16];
        w3c[nt]  = sW3 [nt * 16 + c16];
    }
    #pragma unroll
    for (int mt = 0; mt < 2; ++mt)
        #pragma unroll
        for (int r = 0; r < 4; ++r) {
            int mrow = wrow + mt * 16 + q * 4 + r;
            unsigned int u = uA[(mrow + 2) * AST + l];
            float xt = __uint_as_float(u & 0xFFFF0000u) + __uint_as_float(u << 16);
            #pragma unroll
            for (int nt = 0; nt < 4; ++nt)
                z1[mt][nt][r] += xt * w1lc[nt] + b1c[nt];
        }
    __syncthreads();   // all x / W1-chunk reads done

    // write a1 = leaky(z1) hi/lo packed -> region A; stage W2 -> region B
    #pragma unroll
    for (int mt = 0; mt < 2; ++mt)
        #pragma unroll
        for (int r = 0; r < 4; ++r) {
            int mrow = wrow + mt * 16 + q * 4 + r;
            #pragma unroll
            for (int nt = 0; nt < 4; ++nt) {
                float zv = z1[mt][nt][r];
                float a1 = zv > 0.f ? zv : 0.01f * zv;
                uA[mrow * AST + nt * 16 + c16] = packbf(a1);
            }
        }
    for (int e = tid; e < 1024; e += 256) {
        int g = e >> 4, h0 = (e & 15) * 4;
        float4 v = *(const float4*)(W2l + g * 64 + h0);
        u32x4 pk = { packbf(v.x), packbf(v.y), packbf(v.z), packbf(v.w) };
        *(u32x4*)&uB[g * BST + h0] = pk;
    }
    __syncthreads();

    // ---- stage 2a: z2 = a1 @ W2' (K=64, 3-pass split) ----
    f32x4 z2a[2][4];
    #pragma unroll
    for (int mt = 0; mt < 2; ++mt)
        #pragma unroll
        for (int nt = 0; nt < 4; ++nt) z2a[mt][nt] = (f32x4){0.f,0.f,0.f,0.f};
    #pragma unroll
    for (int kc2 = 0; kc2 < 2; ++kc2) {
        bf16x8 ah[2], al[2], bh[4], bl[4];
        #pragma unroll
        for (int mt = 0; mt < 2; ++mt)
            loadfrag(&uA[(wrow + mt * 16 + c16) * AST + kc2 * 32 + q * 8], &ah[mt], &al[mt]);
        #pragma unroll
        for (int nt = 0; nt < 4; ++nt)
            loadfrag(&uB[(nt * 16 + c16) * BST + kc2 * 32 + q * 8], &bh[nt], &bl[nt]);
        #pragma unroll
        for (int mt = 0; mt < 2; ++mt)
            #pragma unroll
            for (int nt = 0; nt < 4; ++nt) {
                z2a[mt][nt] = __builtin_amdgcn_mfma_f32_16x16x32_bf16(ah[mt], bh[nt], z2a[mt][nt], 0, 0, 0);
                z2a[mt][nt] = __builtin_amdgcn_mfma_f32_16x16x32_bf16(al[mt], bh[nt], z2a[mt][nt], 0, 0, 0);
                z2a[mt][nt] = __builtin_amdgcn_mfma_f32_16x16x32_bf16(ah[mt], bl[nt], z2a[mt][nt], 0, 0, 0);
            }
    }
    __syncthreads();   // a1 reads done

    // write t1 = dleaky(z1)*w1_last hi/lo packed -> region A
    #pragma unroll
    for (int mt = 0; mt < 2; ++mt)
        #pragma unroll
        for (int r = 0; r < 4; ++r) {
            int mrow = wrow + mt * 16 + q * 4 + r;
            #pragma unroll
            for (int nt = 0; nt < 4; ++nt) {
                float d1 = z1[mt][nt][r] > 0.f ? 1.0f : 0.01f;
                uA[mrow * AST + nt * 16 + c16] = packbf(d1 * w1lc[nt]);
            }
        }
    __syncthreads();

    // ---- stage 2b: z2t = t1 @ W2' (K=64, 3-pass split) ----
    f32x4 z2t[2][4];
    #pragma unroll
    for (int mt = 0; mt < 2; ++mt)
        #pragma unroll
        for (int nt = 0; nt < 4; ++nt) z2t[mt][nt] = (f32x4){0.f,0.f,0.f,0.f};
    #pragma unroll
    for (int kc2 = 0; kc2 < 2; ++kc2) {
        bf16x8 ah[2], al[2], bh[4], bl[4];
        #pragma unroll
        for (int mt = 0; mt < 2; ++mt)
            loadfrag(&uA[(wrow + mt * 16 + c16) * AST + kc2 * 32 + q * 8], &ah[mt], &al[mt]);
        #pragma unroll
        for (int nt = 0; nt < 4; ++nt)
            loadfrag(&uB[(nt * 16 + c16) * BST + kc2 * 32 + q * 8], &bh[nt], &bl[nt]);
        #pragma unroll
        for (int mt = 0; mt < 2; ++mt)
            #pragma unroll
            for (int nt = 0; nt < 4; ++nt) {
                z2t[mt][nt] = __builtin_amdgcn_mfma_f32_16x16x32_bf16(ah[mt], bh[nt], z2t[mt][nt], 0, 0, 0);
                z2t[mt][nt] = __builtin_amdgcn_mfma_f32_16x16x32_bf16(al[mt], bh[nt], z2t[mt][nt], 0, 0, 0);
                z2t[mt][nt] = __builtin_amdgcn_mfma_f32_16x16x32_bf16(ah[mt], bl[nt], z2t[mt][nt], 0, 0, 0);
            }
    }

    // ---- stage 3 epilogue (fp32) ----
    const float b3v = b3[l];
    float* outd = out + (size_t)NTOT * 64;
    #pragma unroll
    for (int mt = 0; mt < 2; ++mt)
        #pragma unroll
        for (int r = 0; r < 4; ++r) {
            float po = 0.f, pd = 0.f;
            #pragma unroll
            for (int nt = 0; nt < 4; ++nt) {
                float zv = z2a[mt][nt][r] + b2c[nt];
                float a2 = zv > 0.f ? zv : 0.01f * zv;
                float d2 = zv > 0.f ? 1.0f : 0.01f;
                po += a2 * w3c[nt];
                pd += d2 * z2t[mt][nt][r] * w3c[nt];
            }
            #pragma unroll
            for (int m = 1; m < 16; m <<= 1) {
                po += __shfl_xor(po, m, 64);
                pd += __shfl_xor(pd, m, 64);
            }
            if (c16 == 0) {
                int n = n_base + wrow + mt * 16 + q * 4 + r;
                out[(size_t)n * 64 + l] = po + b3v;
                atomicAdd(outd + n, logf(fabsf(pd)));
            }
        }
}

extern "C" void kernel_launch(void* const* d_in, const int* in_sizes, int n_in,
                              void* d_out, int out_size, void* d_ws, size_t ws_size,
                              hipStream_t stream) {
    const float* x  = (const float*)d_in[0];
    const float* W1 = (const float*)d_in[1];
    const float* b1 = (const float*)d_in[2];
    const float* W2 = (const float*)d_in[3];
    const float* b2 = (const float*)d_in[4];
    const float* W3 = (const float*)d_in[5];
    const float* b3 = (const float*)d_in[6];
    float* out = (float*)d_out;

    hipLaunchKernelGGL(zero_logdet, dim3(NTOT / 256), dim3(256), 0, stream,
                       out + (size_t)NTOT * 64);

    dim3 grid(64 /*l*/, NTOT / 128 /*n tiles*/);
    hipLaunchKernelGGL(np_prior_mfma2, grid, dim3(256), 0, stream,
                       x, W1, b1, W2, b2, W3, b3, out);
}

// Round 4
// 251.829 us; speedup vs baseline: 4.6786x; 1.2822x over previous
//
#include <hip/hip_runtime.h>
#include <math.h>

#define BB   16
#define TT   1026
#define LEN  1024
#define NTOT (BB*LEN)        // 16384
#define NX   (BB*TT*64)      // 1050624 floats in x
#define AP   68              // LDS act row stride in shorts (bank-conflict-free)

typedef __attribute__((ext_vector_type(8))) short bf16x8;
typedef __attribute__((ext_vector_type(4))) float f32x4;

// ---- ws byte offsets ----
#define OXH   ((size_t)0)                    // XH: NX shorts
#define OXL   (OXH + (size_t)NX*2)           // XL: NX shorts
#define OW1H  (OXL + (size_t)NX*2)           // W1H: 64 l * 8192 shorts (16 frags*64 lanes*8)
#define OW1L  (OW1H + (size_t)64*8192*2)
#define OW2H  (OW1L + (size_t)64*8192*2)     // W2H: 64 l * 4096 shorts (8 frags)
#define OW2L  (OW2H + (size_t)64*4096*2)
#define OVH   (OW2L + (size_t)64*4096*2)
#define OVL   (OVH + (size_t)64*4096*2)
#define ORSV  (OVL + (size_t)64*4096*2)      // f32 [64*64]

__device__ __forceinline__ unsigned int rne16(unsigned int u) {
    return (u + 0x7FFFu + ((u >> 16) & 1u)) >> 16;
}
__device__ __forceinline__ void split2(float v, short* h, short* s) {
    unsigned int u  = __float_as_uint(v);
    unsigned int hi = rne16(u);
    float lof = v - __uint_as_float(hi << 16);
    *h = (short)hi;
    *s = (short)rne16(__float_as_uint(lof));
}

__global__ __launch_bounds__(256)
void zero_logdet(float* __restrict__ p) {
    int i = blockIdx.x * 256 + threadIdx.x;
    if (i < NTOT) p[i] = 0.0f;
}

// x (fp32) -> XH/XL deinterleaved bf16 hi/lo
__global__ __launch_bounds__(256)
void prep_x(const float* __restrict__ x, short* __restrict__ XH, short* __restrict__ XL) {
    int i = (blockIdx.x * 256 + threadIdx.x) * 4;   // grid exact: NX/4 threads
    float4 v = *(const float4*)(x + i);
    float vv[4] = {v.x, v.y, v.z, v.w};
    short hh[4], ll[4];
    #pragma unroll
    for (int j = 0; j < 4; ++j) split2(vv[j], &hh[j], &ll[j]);
    *(short4*)&XH[i] = make_short4(hh[0], hh[1], hh[2], hh[3]);
    *(short4*)&XL[i] = make_short4(ll[0], ll[1], ll[2], ll[3]);
}

// weights -> frag-major hi/lo arrays + V = w1_last .* W2 + rowsumV
__global__ __launch_bounds__(256)
void prep_w(const float* __restrict__ W1, const float* __restrict__ W2,
            short* __restrict__ W1H, short* __restrict__ W1L,
            short* __restrict__ W2H, short* __restrict__ W2L,
            short* __restrict__ VH,  short* __restrict__ VL,
            float* __restrict__ RSV)
{
    const int l = blockIdx.x, tid = threadIdx.x;
    const float* W1l = W1 + (size_t)l * 64 * 129;
    const float* W2l = W2 + (size_t)l * 64 * 64;

    // W1 frags: fid = fk*4+nt (fk: K-block of 32, nt: col-block of 16)
    for (int e = tid; e < 1024; e += 256) {
        int fid = e >> 6, lane = e & 63;
        int fk = fid >> 2, nt = fid & 3;
        int h  = nt * 16 + (lane & 15);
        int f0 = fk * 32 + (lane >> 4) * 8;
        const float* src = W1l + h * 129 + f0;
        size_t o = (size_t)l * 8192 + (size_t)e * 8;
        #pragma unroll
        for (int j = 0; j < 8; ++j) {
            short h_, l_; split2(src[j], &h_, &l_);
            W1H[o + j] = h_; W1L[o + j] = l_;
        }
    }
    // W2 / V frags: fid = kc2*4+nt
    for (int e = tid; e < 512; e += 256) {
        int fid = e >> 6, lane = e & 63;
        int kc2 = fid >> 2, nt = fid & 3;
        int g  = nt * 16 + (lane & 15);
        int h0 = kc2 * 32 + (lane >> 4) * 8;
        size_t o = (size_t)l * 4096 + (size_t)e * 8;
        #pragma unroll
        for (int j = 0; j < 8; ++j) {
            float w2v  = W2l[g * 64 + h0 + j];
            float w1lv = W1l[(h0 + j) * 129 + 128];
            short h_, l_;
            split2(w2v, &h_, &l_);        W2H[o + j] = h_; W2L[o + j] = l_;
            split2(w2v * w1lv, &h_, &l_); VH[o + j]  = h_; VL[o + j]  = l_;
        }
    }
    if (tid < 64) {
        float s = 0.f;
        for (int h = 0; h < 64; ++h) s += W2l[tid * 64 + h] * W1l[h * 129 + 128];
        RSV[l * 64 + tid] = s;
    }
}

__global__ __launch_bounds__(256, 3)
void np_main(const float* __restrict__ x,  const float* __restrict__ W1,
             const float* __restrict__ b1, const float* __restrict__ b2,
             const float* __restrict__ W3, const float* __restrict__ b3,
             const short* __restrict__ XH, const short* __restrict__ XL,
             const short* __restrict__ W1H, const short* __restrict__ W1L,
             const short* __restrict__ W2H, const short* __restrict__ W2L,
             const short* __restrict__ VH,  const short* __restrict__ VL,
             const float* __restrict__ RSV, float* __restrict__ out)
{
    __shared__ short a1h[128 * AP], a1l[128 * AP], msk[128 * AP];

    const int l = blockIdx.x, tid = threadIdx.x;
    const int nb = blockIdx.y * 128;
    const int bb = nb >> 10, t0 = nb & 1023;
    const int lane = tid & 63, wid = tid >> 6;
    const int q = lane >> 4, c16 = lane & 15;
    const int wrow = wid * 32;
    const size_t xrow0 = (size_t)(bb * TT + t0);

    // ---- stage 1: z1 = x_lags @ W1' (K=128, 3-pass split bf16), frags from global ----
    f32x4 z1[2][4];
    #pragma unroll
    for (int mt = 0; mt < 2; ++mt)
        #pragma unroll
        for (int nt = 0; nt < 4; ++nt) z1[mt][nt] = (f32x4){0.f, 0.f, 0.f, 0.f};

    const short* w1hb = W1H + (size_t)l * 8192;
    const short* w1lb = W1L + (size_t)l * 8192;
    #pragma unroll
    for (int fk = 0; fk < 4; ++fk) {
        const int colx = (fk & 1) * 32 + q * 8;
        const int rofs = fk >> 1;                       // lag row offset
        bf16x8 ah[2], al[2], bh[4], bl[4];
        #pragma unroll
        for (int mt = 0; mt < 2; ++mt) {
            size_t xo = (xrow0 + wrow + mt * 16 + c16 + rofs) * 64 + colx;
            ah[mt] = *(const bf16x8*)(XH + xo);
            al[mt] = *(const bf16x8*)(XL + xo);
        }
        #pragma unroll
        for (int nt = 0; nt < 4; ++nt) {
            size_t wo = (size_t)((fk * 4 + nt) * 64 + lane) * 8;
            bh[nt] = *(const bf16x8*)(w1hb + wo);
            bl[nt] = *(const bf16x8*)(w1lb + wo);
        }
        #pragma unroll
        for (int mt = 0; mt < 2; ++mt)
            #pragma unroll
            for (int nt = 0; nt < 4; ++nt) {
                z1[mt][nt] = __builtin_amdgcn_mfma_f32_16x16x32_bf16(ah[mt], bh[nt], z1[mt][nt], 0, 0, 0);
                z1[mt][nt] = __builtin_amdgcn_mfma_f32_16x16x32_bf16(al[mt], bh[nt], z1[mt][nt], 0, 0, 0);
                z1[mt][nt] = __builtin_amdgcn_mfma_f32_16x16x32_bf16(ah[mt], bl[nt], z1[mt][nt], 0, 0, 0);
            }
    }

    // finalize z1 fp32: + x_t*w1_last + b1 (x_t exact from fp32 x); write a1 hi/lo + mask
    float w1lc[4], b1c[4];
    #pragma unroll
    for (int nt = 0; nt < 4; ++nt) {
        w1lc[nt] = W1[(size_t)(l * 64 + nt * 16 + c16) * 129 + 128];
        b1c[nt]  = b1[l * 64 + nt * 16 + c16];
    }
    #pragma unroll
    for (int mt = 0; mt < 2; ++mt)
        #pragma unroll
        for (int r = 0; r < 4; ++r) {
            int mrow = wrow + mt * 16 + q * 4 + r;
            float xt = x[(xrow0 + mrow + 2) * 64 + l];
            #pragma unroll
            for (int nt = 0; nt < 4; ++nt) {
                float z  = z1[mt][nt][r] + xt * w1lc[nt] + b1c[nt];
                float av = z > 0.f ? z : 0.01f * z;
                int idx = mrow * AP + nt * 16 + c16;
                short h_, l_; split2(av, &h_, &l_);
                a1h[idx] = h_;
                a1l[idx] = l_;
                msk[idx] = z > 0.f ? (short)0x3F80 : (short)0;   // bf16 1.0 / 0.0
            }
        }
    __syncthreads();

    // ---- stage 2 fused: z2a = a1@W2' (3-pass), z2m = mask@V' (2-pass, exact mask) ----
    f32x4 z2a[2][4], z2m[2][4];
    #pragma unroll
    for (int mt = 0; mt < 2; ++mt)
        #pragma unroll
        for (int nt = 0; nt < 4; ++nt) {
            z2a[mt][nt] = (f32x4){0.f, 0.f, 0.f, 0.f};
            z2m[mt][nt] = (f32x4){0.f, 0.f, 0.f, 0.f};
        }
    const short* w2hb = W2H + (size_t)l * 4096;
    const short* w2lb = W2L + (size_t)l * 4096;
    const short* vhb  = VH  + (size_t)l * 4096;
    const short* vlb  = VL  + (size_t)l * 4096;
    #pragma unroll
    for (int kc2 = 0; kc2 < 2; ++kc2) {
        bf16x8 ah2[2], al2[2], mf[2];
        #pragma unroll
        for (int mt = 0; mt < 2; ++mt) {
            int ao = (wrow + mt * 16 + c16) * AP + kc2 * 32 + q * 8;
            ah2[mt] = *(const bf16x8*)&a1h[ao];
            al2[mt] = *(const bf16x8*)&a1l[ao];
            mf[mt]  = *(const bf16x8*)&msk[ao];
        }
        {   // z2a block (W2 frags live only here -> lower VGPR peak)
            bf16x8 wh[4], wl[4];
            #pragma unroll
            for (int nt = 0; nt < 4; ++nt) {
                size_t wo = (size_t)((kc2 * 4 + nt) * 64 + lane) * 8;
                wh[nt] = *(const bf16x8*)(w2hb + wo);
                wl[nt] = *(const bf16x8*)(w2lb + wo);
            }
            #pragma unroll
            for (int mt = 0; mt < 2; ++mt)
                #pragma unroll
                for (int nt = 0; nt < 4; ++nt) {
                    z2a[mt][nt] = __builtin_amdgcn_mfma_f32_16x16x32_bf16(ah2[mt], wh[nt], z2a[mt][nt], 0, 0, 0);
                    z2a[mt][nt] = __builtin_amdgcn_mfma_f32_16x16x32_bf16(al2[mt], wh[nt], z2a[mt][nt], 0, 0, 0);
                    z2a[mt][nt] = __builtin_amdgcn_mfma_f32_16x16x32_bf16(ah2[mt], wl[nt], z2a[mt][nt], 0, 0, 0);
                }
        }
        {   // z2m block
            bf16x8 vh[4], vl[4];
            #pragma unroll
            for (int nt = 0; nt < 4; ++nt) {
                size_t wo = (size_t)((kc2 * 4 + nt) * 64 + lane) * 8;
                vh[nt] = *(const bf16x8*)(vhb + wo);
                vl[nt] = *(const bf16x8*)(vlb + wo);
            }
            #pragma unroll
            for (int mt = 0; mt < 2; ++mt)
                #pragma unroll
                for (int nt = 0; nt < 4; ++nt) {
                    z2m[mt][nt] = __builtin_amdgcn_mfma_f32_16x16x32_bf16(mf[mt], vh[nt], z2m[mt][nt], 0, 0, 0);
                    z2m[mt][nt] = __builtin_amdgcn_mfma_f32_16x16x32_bf16(mf[mt], vl[nt], z2m[mt][nt], 0, 0, 0);
                }
        }
    }

    // ---- epilogue: z2t = 0.01*rowsumV + 0.99*z2m; reduce over g ----
    float b2c[4], w3c[4], rsv[4];
    #pragma unroll
    for (int nt = 0; nt < 4; ++nt) {
        int g = nt * 16 + c16;
        b2c[nt] = b2[l * 64 + g];
        w3c[nt] = W3[l * 64 + g];
        rsv[nt] = RSV[l * 64 + g];
    }
    const float b3v = b3[l];
    float* outd = out + (size_t)NTOT * 64;
    #pragma unroll
    for (int mt = 0; mt < 2; ++mt)
        #pragma unroll
        for (int r = 0; r < 4; ++r) {
            float po = 0.f, pd = 0.f;
            #pragma unroll
            for (int nt = 0; nt < 4; ++nt) {
                float z  = z2a[mt][nt][r] + b2c[nt];
                float a2 = z > 0.f ? z : 0.01f * z;
                float d2 = z > 0.f ? 1.0f : 0.01f;
                float zt = 0.01f * rsv[nt] + 0.99f * z2m[mt][nt][r];
                po += a2 * w3c[nt];
                pd += d2 * zt * w3c[nt];
            }
            #pragma unroll
            for (int m = 1; m < 16; m <<= 1) {
                po += __shfl_xor(po, m, 64);
                pd += __shfl_xor(pd, m, 64);
            }
            if (c16 == 0) {
                int n = nb + wrow + mt * 16 + q * 4 + r;
                out[(size_t)n * 64 + l] = po + b3v;
                atomicAdd(outd + n, __logf(fabsf(pd)));
            }
        }
}

extern "C" void kernel_launch(void* const* d_in, const int* in_sizes, int n_in,
                              void* d_out, int out_size, void* d_ws, size_t ws_size,
                              hipStream_t stream) {
    const float* x  = (const float*)d_in[0];
    const float* W1 = (const float*)d_in[1];
    const float* b1 = (const float*)d_in[2];
    const float* W2 = (const float*)d_in[3];
    const float* b2 = (const float*)d_in[4];
    const float* W3 = (const float*)d_in[5];
    const float* b3 = (const float*)d_in[6];
    float* out = (float*)d_out;
    char* ws = (char*)d_ws;

    short* XH  = (short*)(ws + OXH);
    short* XL  = (short*)(ws + OXL);
    short* W1Hp = (short*)(ws + OW1H);
    short* W1Lp = (short*)(ws + OW1L);
    short* W2Hp = (short*)(ws + OW2H);
    short* W2Lp = (short*)(ws + OW2L);
    short* VHp  = (short*)(ws + OVH);
    short* VLp  = (short*)(ws + OVL);
    float* RSVp = (float*)(ws + ORSV);

    hipLaunchKernelGGL(prep_x, dim3(NX / 1024), dim3(256), 0, stream, x, XH, XL);
    hipLaunchKernelGGL(prep_w, dim3(64), dim3(256), 0, stream,
                       W1, W2, W1Hp, W1Lp, W2Hp, W2Lp, VHp, VLp, RSVp);
    hipLaunchKernelGGL(zero_logdet, dim3(NTOT / 256), dim3(256), 0, stream,
                       out + (size_t)NTOT * 64);
    dim3 grid(64 /*l*/, NTOT / 128 /*n tiles*/);
    hipLaunchKernelGGL(np_main, grid, dim3(256), 0, stream,
                       x, W1, b1, b2, W3, b3,
                       XH, XL, W1Hp, W1Lp, W2Hp, W2Lp, VHp, VLp, RSVp, out);
}

// Round 6
// 224.208 us; speedup vs baseline: 5.2550x; 1.1232x over previous
//
#include <hip/hip_runtime.h>
#include <math.h>

#define BB   16
#define TT   1026
#define LEN  1024
#define NTOT (BB*LEN)        // 16384
#define NX   (BB*TT*64)      // 1050624 floats in x
#define AP   68              // LDS act row stride in shorts (measured conflict-free r4)

typedef __attribute__((ext_vector_type(8))) short bf16x8;
typedef __attribute__((ext_vector_type(4))) float f32x4;

// ---- ws byte offsets ----
#define OXH   ((size_t)0)                    // XH: NX shorts
#define OXL   (OXH + (size_t)NX*2)           // XL: NX shorts
#define OW1H  (OXL + (size_t)NX*2)           // W1H: 64 l * 8192 shorts (16 frags*64 lanes*8)
#define OW1L  (OW1H + (size_t)64*8192*2)
#define OW2H  (OW1L + (size_t)64*8192*2)     // W2H: 64 l * 4096 shorts (8 frags)
#define OW2L  (OW2H + (size_t)64*4096*2)
#define OVH   (OW2L + (size_t)64*4096*2)
#define OVL   (OVH + (size_t)64*4096*2)
#define ORSV  (OVL + (size_t)64*4096*2)      // f32 [64*64]

__device__ __forceinline__ unsigned int rne16(unsigned int u) {
    return (u + 0x7FFFu + ((u >> 16) & 1u)) >> 16;
}
__device__ __forceinline__ void split2(float v, short* h, short* s) {
    unsigned int u  = __float_as_uint(v);
    unsigned int hi = rne16(u);
    float lof = v - __uint_as_float(hi << 16);
    *h = (short)hi;
    *s = (short)rne16(__float_as_uint(lof));
}
// mask frag from sign bits of a1h frag: 0x3F80 (bf16 1.0) where positive else 0
__device__ __forceinline__ bf16x8 maskfrag(bf16x8 a) {
    union { bf16x8 v; unsigned int u[4]; } A, M;
    A.v = a;
    #pragma unroll
    for (int j = 0; j < 4; ++j) {
        unsigned int t = (~A.u[j]) & 0x80008000u;   // 0x8000 in halves that are >= +0
        M.u[j] = (t >> 15) * 0x3F80u;               // -> 0x3F80 per positive half
    }
    return M.v;
}

// ---- fused prep: x->XH/XL | weights->frag-major hi/lo + V + rowsumV | zero logdet ----
__global__ __launch_bounds__(256)
void prep_all(const float* __restrict__ x, const float* __restrict__ W1,
              const float* __restrict__ W2,
              short* __restrict__ XH, short* __restrict__ XL,
              short* __restrict__ W1H, short* __restrict__ W1L,
              short* __restrict__ W2H, short* __restrict__ W2L,
              short* __restrict__ VH,  short* __restrict__ VL,
              float* __restrict__ RSV, float* __restrict__ logdet)
{
    const int b = blockIdx.x, tid = threadIdx.x;
    if (b < 1026) {                       // x: 1026 blocks * 256 thr * 4 = NX exactly
        int i = (b * 256 + tid) * 4;
        float4 v = *(const float4*)(x + i);
        float vv[4] = {v.x, v.y, v.z, v.w};
        short hh[4], ll[4];
        #pragma unroll
        for (int j = 0; j < 4; ++j) split2(vv[j], &hh[j], &ll[j]);
        *(short4*)&XH[i] = make_short4(hh[0], hh[1], hh[2], hh[3]);
        *(short4*)&XL[i] = make_short4(ll[0], ll[1], ll[2], ll[3]);
    } else if (b < 1090) {                // weights: one block per l
        const int l = b - 1026;
        const float* W1l = W1 + (size_t)l * 64 * 129;
        const float* W2l = W2 + (size_t)l * 64 * 64;
        for (int e = tid; e < 1024; e += 256) {       // W1 frags: fid = fk*4+nt
            int fid = e >> 6, lane = e & 63;
            int fk = fid >> 2, nt = fid & 3;
            int h  = nt * 16 + (lane & 15);
            int f0 = fk * 32 + (lane >> 4) * 8;
            const float* src = W1l + h * 129 + f0;
            size_t o = (size_t)l * 8192 + (size_t)e * 8;
            #pragma unroll
            for (int j = 0; j < 8; ++j) {
                short h_, l_; split2(src[j], &h_, &l_);
                W1H[o + j] = h_; W1L[o + j] = l_;
            }
        }
        for (int e = tid; e < 512; e += 256) {        // W2 / V frags: fid = kc2*4+nt
            int fid = e >> 6, lane = e & 63;
            int kc2 = fid >> 2, nt = fid & 3;
            int g  = nt * 16 + (lane & 15);
            int h0 = kc2 * 32 + (lane >> 4) * 8;
            size_t o = (size_t)l * 4096 + (size_t)e * 8;
            #pragma unroll
            for (int j = 0; j < 8; ++j) {
                float w2v  = W2l[g * 64 + h0 + j];
                float w1lv = W1l[(h0 + j) * 129 + 128];
                short h_, l_;
                split2(w2v, &h_, &l_);        W2H[o + j] = h_; W2L[o + j] = l_;
                split2(w2v * w1lv, &h_, &l_); VH[o + j]  = h_; VL[o + j]  = l_;
            }
        }
        if (tid < 64) {
            float s = 0.f;
            for (int h = 0; h < 64; ++h) s += W2l[tid * 64 + h] * W1l[h * 129 + 128];
            RSV[l * 64 + tid] = s;
        }
    } else {                              // zero logdet: 64 blocks * 256 = NTOT
        logdet[(b - 1090) * 256 + tid] = 0.0f;
    }
}

__global__ __launch_bounds__(256, 4)
void np_main(const float* __restrict__ x,  const float* __restrict__ W1,
             const float* __restrict__ b1, const float* __restrict__ b2,
             const float* __restrict__ W3, const float* __restrict__ b3,
             const short* __restrict__ XH, const short* __restrict__ XL,
             const short* __restrict__ W1H, const short* __restrict__ W1L,
             const short* __restrict__ W2H, const short* __restrict__ W2L,
             const short* __restrict__ VH,  const short* __restrict__ VL,
             const float* __restrict__ RSV, float* __restrict__ out)
{
    // Wave-private LDS, no __syncthreads. INVARIANT: wave `wid` may touch ONLY
    // shorts [wid*32*AP, (wid+1)*32*AP) of each array — a1 rows AND epilogue
    // scratch both live inside the wave's own quarter (r5's race: scratch at
    // float offset wid*544 crossed into the next wave's rows; now wid*1088).
    __shared__ __align__(16) short a1h[128 * AP];
    __shared__ __align__(16) short a1l[128 * AP];

    const int l = blockIdx.x, tid = threadIdx.x;
    const int nb = blockIdx.y * 128;
    const int bb = nb >> 10, t0 = nb & 1023;
    const int lane = tid & 63, wid = tid >> 6;
    const int q = lane >> 4, c16 = lane & 15;
    const int wrow = wid * 32;
    const size_t xrow0 = (size_t)(bb * TT + t0);

    // ---- stage 1: z1 = x_lags @ W1' (K=128, 3-pass split bf16), frags from global ----
    f32x4 z1[2][4];
    #pragma unroll
    for (int mt = 0; mt < 2; ++mt)
        #pragma unroll
        for (int nt = 0; nt < 4; ++nt) z1[mt][nt] = (f32x4){0.f, 0.f, 0.f, 0.f};

    const short* w1hb = W1H + (size_t)l * 8192;
    const short* w1lb = W1L + (size_t)l * 8192;
    #pragma unroll
    for (int fk = 0; fk < 4; ++fk) {
        const int colx = (fk & 1) * 32 + q * 8;
        const int rofs = fk >> 1;                       // lag row offset
        bf16x8 ah[2], al[2], bh[4], bl[4];
        #pragma unroll
        for (int mt = 0; mt < 2; ++mt) {
            size_t xo = (xrow0 + wrow + mt * 16 + c16 + rofs) * 64 + colx;
            ah[mt] = *(const bf16x8*)(XH + xo);
            al[mt] = *(const bf16x8*)(XL + xo);
        }
        #pragma unroll
        for (int nt = 0; nt < 4; ++nt) {
            size_t wo = (size_t)((fk * 4 + nt) * 64 + lane) * 8;
            bh[nt] = *(const bf16x8*)(w1hb + wo);
            bl[nt] = *(const bf16x8*)(w1lb + wo);
        }
        #pragma unroll
        for (int mt = 0; mt < 2; ++mt)
            #pragma unroll
            for (int nt = 0; nt < 4; ++nt) {
                z1[mt][nt] = __builtin_amdgcn_mfma_f32_16x16x32_bf16(ah[mt], bh[nt], z1[mt][nt], 0, 0, 0);
                z1[mt][nt] = __builtin_amdgcn_mfma_f32_16x16x32_bf16(al[mt], bh[nt], z1[mt][nt], 0, 0, 0);
                z1[mt][nt] = __builtin_amdgcn_mfma_f32_16x16x32_bf16(ah[mt], bl[nt], z1[mt][nt], 0, 0, 0);
            }
    }

    // finalize z1 fp32: + x_t*w1_last + b1 ; write a1 hi/lo (trunc split, 4 ops)
    float w1lc[4], b1c[4];
    #pragma unroll
    for (int nt = 0; nt < 4; ++nt) {
        w1lc[nt] = W1[(size_t)(l * 64 + nt * 16 + c16) * 129 + 128];
        b1c[nt]  = b1[l * 64 + nt * 16 + c16];
    }
    #pragma unroll
    for (int mt = 0; mt < 2; ++mt)
        #pragma unroll
        for (int r = 0; r < 4; ++r) {
            int mrow = wrow + mt * 16 + q * 4 + r;
            float xt = x[(xrow0 + mrow + 2) * 64 + l];
            #pragma unroll
            for (int nt = 0; nt < 4; ++nt) {
                float z  = z1[mt][nt][r] + xt * w1lc[nt] + b1c[nt];
                float av = z > 0.f ? z : 0.01f * z;
                unsigned int u = __float_as_uint(av);
                int idx = mrow * AP + nt * 16 + c16;
                a1h[idx] = (short)(u >> 16);
                float res = av - __uint_as_float(u & 0xFFFF0000u);
                a1l[idx] = (short)(__float_as_uint(res) >> 16);
            }
        }

    // ---- stage 2 fused (wave-private LDS, no barrier):
    //      z2a = a1@W2' (3-pass), z2m = mask@V' (2-pass; mask from a1h sign) ----
    f32x4 z2a[2][4], z2m[2][4];
    #pragma unroll
    for (int mt = 0; mt < 2; ++mt)
        #pragma unroll
        for (int nt = 0; nt < 4; ++nt) {
            z2a[mt][nt] = (f32x4){0.f, 0.f, 0.f, 0.f};
            z2m[mt][nt] = (f32x4){0.f, 0.f, 0.f, 0.f};
        }
    const short* w2hb = W2H + (size_t)l * 4096;
    const short* w2lb = W2L + (size_t)l * 4096;
    const short* vhb  = VH  + (size_t)l * 4096;
    const short* vlb  = VL  + (size_t)l * 4096;
    #pragma unroll
    for (int kc2 = 0; kc2 < 2; ++kc2) {
        bf16x8 ah2[2], al2[2], mf[2];
        #pragma unroll
        for (int mt = 0; mt < 2; ++mt) {
            int ao = (wrow + mt * 16 + c16) * AP + kc2 * 32 + q * 8;
            ah2[mt] = *(const bf16x8*)&a1h[ao];
            al2[mt] = *(const bf16x8*)&a1l[ao];
            mf[mt]  = maskfrag(ah2[mt]);
        }
        {   // z2a block
            bf16x8 wh[4], wl[4];
            #pragma unroll
            for (int nt = 0; nt < 4; ++nt) {
                size_t wo = (size_t)((kc2 * 4 + nt) * 64 + lane) * 8;
                wh[nt] = *(const bf16x8*)(w2hb + wo);
                wl[nt] = *(const bf16x8*)(w2lb + wo);
            }
            #pragma unroll
            for (int mt = 0; mt < 2; ++mt)
                #pragma unroll
                for (int nt = 0; nt < 4; ++nt) {
                    z2a[mt][nt] = __builtin_amdgcn_mfma_f32_16x16x32_bf16(ah2[mt], wh[nt], z2a[mt][nt], 0, 0, 0);
                    z2a[mt][nt] = __builtin_amdgcn_mfma_f32_16x16x32_bf16(al2[mt], wh[nt], z2a[mt][nt], 0, 0, 0);
                    z2a[mt][nt] = __builtin_amdgcn_mfma_f32_16x16x32_bf16(ah2[mt], wl[nt], z2a[mt][nt], 0, 0, 0);
                }
        }
        {   // z2m block
            bf16x8 vh[4], vl[4];
            #pragma unroll
            for (int nt = 0; nt < 4; ++nt) {
                size_t wo = (size_t)((kc2 * 4 + nt) * 64 + lane) * 8;
                vh[nt] = *(const bf16x8*)(vhb + wo);
                vl[nt] = *(const bf16x8*)(vlb + wo);
            }
            #pragma unroll
            for (int mt = 0; mt < 2; ++mt)
                #pragma unroll
                for (int nt = 0; nt < 4; ++nt) {
                    z2m[mt][nt] = __builtin_amdgcn_mfma_f32_16x16x32_bf16(mf[mt], vh[nt], z2m[mt][nt], 0, 0, 0);
                    z2m[mt][nt] = __builtin_amdgcn_mfma_f32_16x16x32_bf16(mf[mt], vl[nt], z2m[mt][nt], 0, 0, 0);
                }
        }
    }

    // ---- epilogue: partials -> wave-private LDS transpose -> coalesced reduce ----
    float b2c[4], w3c[4], rsv[4];
    #pragma unroll
    for (int nt = 0; nt < 4; ++nt) {
        int g = nt * 16 + c16;
        b2c[nt] = b2[l * 64 + g];
        w3c[nt] = W3[l * 64 + g];
        rsv[nt] = RSV[l * 64 + g];
    }
    // scratch INSIDE the wave's own quarter: quarter = 2176 shorts = 1088 floats,
    // need 544 floats -> zero overlap with any other wave's rows.
    float* spo = (float*)a1h + wid * 1088;
    float* spd = (float*)a1l + wid * 1088;
    #pragma unroll
    for (int mt = 0; mt < 2; ++mt)
        #pragma unroll
        for (int r = 0; r < 4; ++r) {
            float po = 0.f, pd = 0.f;
            #pragma unroll
            for (int nt = 0; nt < 4; ++nt) {
                float z  = z2a[mt][nt][r] + b2c[nt];
                float a2 = z > 0.f ? z : 0.01f * z;
                float d2 = z > 0.f ? 1.0f : 0.01f;
                float zt = 0.01f * rsv[nt] + 0.99f * z2m[mt][nt][r];
                po += a2 * w3c[nt];
                pd += d2 * zt * w3c[nt];
            }
            int row = mt * 16 + q * 4 + r;
            spo[row * 17 + c16] = po;
            spd[row * 17 + c16] = pd;
        }
    __threadfence_block();   // drain wave's LDS writes before cross-lane read

    {
        int row = lane >> 1;
        const float* sp = (lane & 1) ? (spd + row * 17) : (spo + row * 17);
        float s = 0.f;
        #pragma unroll
        for (int j = 0; j < 16; ++j) s += sp[j];
        int n = nb + wrow + row;
        if (lane & 1) {
            atomicAdd(out + (size_t)NTOT * 64 + n, __logf(fabsf(s)));
        } else {
            out[(size_t)n * 64 + l] = s + b3[l];
        }
    }
}

extern "C" void kernel_launch(void* const* d_in, const int* in_sizes, int n_in,
                              void* d_out, int out_size, void* d_ws, size_t ws_size,
                              hipStream_t stream) {
    const float* x  = (const float*)d_in[0];
    const float* W1 = (const float*)d_in[1];
    const float* b1 = (const float*)d_in[2];
    const float* W2 = (const float*)d_in[3];
    const float* b2 = (const float*)d_in[4];
    const float* W3 = (const float*)d_in[5];
    const float* b3 = (const float*)d_in[6];
    float* out = (float*)d_out;
    char* ws = (char*)d_ws;

    short* XH   = (short*)(ws + OXH);
    short* XL   = (short*)(ws + OXL);
    short* W1Hp = (short*)(ws + OW1H);
    short* W1Lp = (short*)(ws + OW1L);
    short* W2Hp = (short*)(ws + OW2H);
    short* W2Lp = (short*)(ws + OW2L);
    short* VHp  = (short*)(ws + OVH);
    short* VLp  = (short*)(ws + OVL);
    float* RSVp = (float*)(ws + ORSV);

    hipLaunchKernelGGL(prep_all, dim3(1026 + 64 + 64), dim3(256), 0, stream,
                       x, W1, W2, XH, XL, W1Hp, W1Lp, W2Hp, W2Lp, VHp, VLp, RSVp,
                       out + (size_t)NTOT * 64);
    dim3 grid(64 /*l*/, NTOT / 128 /*n tiles*/);
    hipLaunchKernelGGL(np_main, grid, dim3(256), 0, stream,
                       x, W1, b1, b2, W3, b3,
                       XH, XL, W1Hp, W1Lp, W2Hp, W2Lp, VHp, VLp, RSVp, out);
}

// Round 7
// 203.285 us; speedup vs baseline: 5.7959x; 1.1029x over previous
//
#include <hip/hip_runtime.h>
#include <math.h>

#define BB   16
#define TT   1026
#define LEN  1024
#define NTOT (BB*LEN)        // 16384
#define NX   (BB*TT*64)      // 1050624 floats in x
#define AP   68              // LDS act row stride in shorts (measured ~conflict-free r4/r6)

typedef __attribute__((ext_vector_type(8))) short bf16x8;
typedef __attribute__((ext_vector_type(4))) float f32x4;

// ---- ws byte offsets ----
#define OXH   ((size_t)0)                     // XH: NX shorts
#define OXL   (OXH + (size_t)NX*2)            // XL: NX shorts
#define OW1H  (OXL + (size_t)NX*2)            // 64 l * 8192 shorts (16 frags * 64 lanes * 8)
#define OW1L  (OW1H + (size_t)64*8192*2)
#define OW2H  (OW1L + (size_t)64*8192*2)      // 64 l * 4096 shorts (8 frags)
#define OW2L  (OW2H + (size_t)64*4096*2)
#define OWLH  (OW2L + (size_t)64*4096*2)      // w1_last hi split: 64 l * 64 shorts
#define OWLL  (OWLH + (size_t)64*64*2)
#define ORSV  (OWLL + (size_t)64*64*2)        // f32 [64*64]
#define OPD   (ORSV + (size_t)64*64*4)        // f32 [64][16384]  (dJ per l,n)

__device__ __forceinline__ unsigned int rne16(unsigned int u) {
    return (u + 0x7FFFu + ((u >> 16) & 1u)) >> 16;
}
__device__ __forceinline__ void split2(float v, short* h, short* s) {
    unsigned int u  = __float_as_uint(v);
    unsigned int hi = rne16(u);
    float lof = v - __uint_as_float(hi << 16);
    *h = (short)hi;
    *s = (short)rne16(__float_as_uint(lof));
}
// masked-A frag: element = (a1 positive ? w1l_part : 0). Exact: mask in {0,1}.
__device__ __forceinline__ bf16x8 maskand(bf16x8 a, bf16x8 w) {
    union { bf16x8 v; unsigned int u[4]; } A, W, M;
    A.v = a; W.v = w;
    #pragma unroll
    for (int j = 0; j < 4; ++j) {
        unsigned int t = (~A.u[j]) & 0x80008000u;   // sign==0 (positive) halves
        M.u[j] = ((t >> 15) * 0xFFFFu) & W.u[j];    // full-half mask, AND with w1l bits
    }
    return M.v;
}

// ---- fused prep ----
// blocks [0,1026):   x -> XH/XL
// blocks [1026,1410): weight frags (384 blocks * 256 = 98304 = 64*1536 elems)
// blocks [1410,1474): per-l w1_last split + RSV
__global__ __launch_bounds__(256)
void prep_all(const float* __restrict__ x, const float* __restrict__ W1,
              const float* __restrict__ W2,
              short* __restrict__ XH, short* __restrict__ XL,
              short* __restrict__ W1H, short* __restrict__ W1L,
              short* __restrict__ W2H, short* __restrict__ W2L,
              short* __restrict__ WLH, short* __restrict__ WLL,
              float* __restrict__ RSV)
{
    const int b = blockIdx.x, tid = threadIdx.x;
    if (b < 1026) {
        int i = (b * 256 + tid) * 4;
        float4 v = *(const float4*)(x + i);
        float vv[4] = {v.x, v.y, v.z, v.w};
        short hh[4], ll[4];
        #pragma unroll
        for (int j = 0; j < 4; ++j) split2(vv[j], &hh[j], &ll[j]);
        *(short4*)&XH[i] = make_short4(hh[0], hh[1], hh[2], hh[3]);
        *(short4*)&XL[i] = make_short4(ll[0], ll[1], ll[2], ll[3]);
    } else if (b < 1410) {
        int e = (b - 1026) * 256 + tid;          // 0..98303
        int l = e / 1536, r = e - l * 1536;
        if (r < 1024) {                           // W1 frag elem: fid = fk*4+nt
            int fid = r >> 6, lane = r & 63;
            int fk = fid >> 2, nt = fid & 3;
            int h  = nt * 16 + (lane & 15);
            int f0 = fk * 32 + (lane >> 4) * 8;
            const float* src = W1 + (size_t)l * 8256 + h * 129 + f0;
            size_t o = (size_t)l * 8192 + (size_t)r * 8;
            #pragma unroll
            for (int j = 0; j < 8; ++j) {
                short h_, l_; split2(src[j], &h_, &l_);
                W1H[o + j] = h_; W1L[o + j] = l_;
            }
        } else {                                  // W2 frag elem: fid = kc2*4+nt
            int r2 = r - 1024;
            int fid = r2 >> 6, lane = r2 & 63;
            int kc2 = fid >> 2, nt = fid & 3;
            int g  = nt * 16 + (lane & 15);
            int h0 = kc2 * 32 + (lane >> 4) * 8;
            const float* src = W2 + (size_t)l * 4096 + g * 64 + h0;
            size_t o = (size_t)l * 4096 + (size_t)r2 * 8;
            #pragma unroll
            for (int j = 0; j < 8; ++j) {
                short h_, l_; split2(src[j], &h_, &l_);
                W2H[o + j] = h_; W2L[o + j] = l_;
            }
        }
    } else {
        const int l = b - 1410;
        if (tid < 64) {
            float wl = W1[(size_t)l * 8256 + tid * 129 + 128];
            short h_, l_; split2(wl, &h_, &l_);
            WLH[l * 64 + tid] = h_; WLL[l * 64 + tid] = l_;
            float s = 0.f;
            for (int h = 0; h < 64; ++h)
                s += W2[(size_t)l * 4096 + tid * 64 + h] * W1[(size_t)l * 8256 + h * 129 + 128];
            RSV[l * 64 + tid] = s;
        }
    }
}

// logdet[n] = sum_l log|PD[l][n]|  (coalesced; removes atomics + zero pass)
__global__ __launch_bounds__(256)
void finish_logdet(const float* __restrict__ PD, float* __restrict__ logdet) {
    int i = blockIdx.x * 256 + threadIdx.x;      // grid exact: NTOT
    float acc = 0.f;
    #pragma unroll 8
    for (int l = 0; l < 64; ++l)
        acc += __logf(fabsf(PD[(size_t)l * NTOT + i]));
    logdet[i] = acc;
}

__global__ __launch_bounds__(256, 2)
void np_main(const float* __restrict__ x,  const float* __restrict__ W1,
             const float* __restrict__ b1, const float* __restrict__ b2,
             const float* __restrict__ W3, const float* __restrict__ b3,
             const short* __restrict__ XH, const short* __restrict__ XL,
             const short* __restrict__ W1H, const short* __restrict__ W1L,
             const short* __restrict__ W2H, const short* __restrict__ W2L,
             const short* __restrict__ WLH, const short* __restrict__ WLL,
             const float* __restrict__ RSV, float* __restrict__ PD,
             float* __restrict__ out)
{
    // Wave-private LDS, no __syncthreads. INVARIANT: wave wid touches ONLY
    // shorts [wid*64*AP, (wid+1)*64*AP) of each array. Epilogue scratch
    // (float*)base + wid*2176 == short offset wid*4352 == exactly the wave's
    // own 64 rows; needs 1088 floats of the 2176 available.
    __shared__ __align__(16) short a1h[256 * AP];
    __shared__ __align__(16) short a1l[256 * AP];

    const int l = blockIdx.x, tid = threadIdx.x;
    const int nb = blockIdx.y * 256;
    const int bb = nb >> 10, t0 = nb & 1023;
    const int lane = tid & 63, wid = tid >> 6;
    const int q = lane >> 4, c16 = lane & 15;
    const int wrow = wid * 64;                   // wave's 64 rows within block
    const size_t xrow0 = (size_t)(bb * TT + t0);

    // ---- stage 1: z1[64rows x 64h] = x_lags @ W1' (K=128, 3-pass split) ----
    f32x4 z1[4][4];
    #pragma unroll
    for (int mt = 0; mt < 4; ++mt)
        #pragma unroll
        for (int nt = 0; nt < 4; ++nt) z1[mt][nt] = (f32x4){0.f, 0.f, 0.f, 0.f};

    const short* w1hb = W1H + (size_t)l * 8192;
    const short* w1lb = W1L + (size_t)l * 8192;
    #pragma unroll
    for (int fk = 0; fk < 4; ++fk) {
        const int colx = (fk & 1) * 32 + q * 8;
        const int rofs = fk >> 1;
        bf16x8 ah[4], al[4], bh[4], bl[4];
        #pragma unroll
        for (int mt = 0; mt < 4; ++mt) {
            size_t xo = (xrow0 + wrow + mt * 16 + c16 + rofs) * 64 + colx;
            ah[mt] = *(const bf16x8*)(XH + xo);
            al[mt] = *(const bf16x8*)(XL + xo);
        }
        #pragma unroll
        for (int nt = 0; nt < 4; ++nt) {
            size_t wo = (size_t)((fk * 4 + nt) * 64 + lane) * 8;
            bh[nt] = *(const bf16x8*)(w1hb + wo);
            bl[nt] = *(const bf16x8*)(w1lb + wo);
        }
        #pragma unroll
        for (int mt = 0; mt < 4; ++mt)
            #pragma unroll
            for (int nt = 0; nt < 4; ++nt) {
                z1[mt][nt] = __builtin_amdgcn_mfma_f32_16x16x32_bf16(ah[mt], bh[nt], z1[mt][nt], 0, 0, 0);
                z1[mt][nt] = __builtin_amdgcn_mfma_f32_16x16x32_bf16(al[mt], bh[nt], z1[mt][nt], 0, 0, 0);
                z1[mt][nt] = __builtin_amdgcn_mfma_f32_16x16x32_bf16(ah[mt], bl[nt], z1[mt][nt], 0, 0, 0);
            }
    }

    // finalize z1 fp32: + x_t*w1_last + b1 ; write a1 hi/lo (RNE split)
    float w1lc[4], b1c[4];
    #pragma unroll
    for (int nt = 0; nt < 4; ++nt) {
        w1lc[nt] = W1[(size_t)(l * 64 + nt * 16 + c16) * 129 + 128];
        b1c[nt]  = b1[l * 64 + nt * 16 + c16];
    }
    #pragma unroll
    for (int mt = 0; mt < 4; ++mt)
        #pragma unroll
        for (int r = 0; r < 4; ++r) {
            int mrow = wrow + mt * 16 + q * 4 + r;
            float xt = x[(xrow0 + mrow + 2) * 64 + l];
            #pragma unroll
            for (int nt = 0; nt < 4; ++nt) {
                float z  = z1[mt][nt][r] + xt * w1lc[nt] + b1c[nt];
                float av = z > 0.f ? z : 0.01f * z;
                int idx = mrow * AP + nt * 16 + c16;
                short h_, s_; split2(av, &h_, &s_);
                a1h[idx] = h_;
                a1l[idx] = s_;
            }
        }

    // ---- stage 2 (wave-private, no barrier):
    //   z2a = a1 @ W2'            (3-pass: ah*Wh + al*Wh + ah*Wl)
    //   z2m = (mask.*w1l) @ W2'   (3-pass: mh*Wh + mh*Wl + ml*Wh; mask exact)
    f32x4 z2a[4][4], z2m[4][4];
    #pragma unroll
    for (int mt = 0; mt < 4; ++mt)
        #pragma unroll
        for (int nt = 0; nt < 4; ++nt) {
            z2a[mt][nt] = (f32x4){0.f, 0.f, 0.f, 0.f};
            z2m[mt][nt] = (f32x4){0.f, 0.f, 0.f, 0.f};
        }
    const short* w2hb = W2H + (size_t)l * 4096;
    const short* w2lb = W2L + (size_t)l * 4096;
    #pragma unroll
    for (int kc2 = 0; kc2 < 2; ++kc2) {
        const bf16x8 wlh = *(const bf16x8*)&WLH[l * 64 + kc2 * 32 + q * 8];
        const bf16x8 wll = *(const bf16x8*)&WLL[l * 64 + kc2 * 32 + q * 8];
        bf16x8 ah2[4], al2[4], wh[4], wl2[4];
        #pragma unroll
        for (int mt = 0; mt < 4; ++mt) {
            int ao = (wrow + mt * 16 + c16) * AP + kc2 * 32 + q * 8;
            ah2[mt] = *(const bf16x8*)&a1h[ao];
            al2[mt] = *(const bf16x8*)&a1l[ao];
        }
        #pragma unroll
        for (int nt = 0; nt < 4; ++nt) {
            size_t wo = (size_t)((kc2 * 4 + nt) * 64 + lane) * 8;
            wh[nt]  = *(const bf16x8*)(w2hb + wo);
            wl2[nt] = *(const bf16x8*)(w2lb + wo);
        }
        #pragma unroll
        for (int mt = 0; mt < 4; ++mt)
            #pragma unroll
            for (int nt = 0; nt < 4; ++nt) {
                z2a[mt][nt] = __builtin_amdgcn_mfma_f32_16x16x32_bf16(ah2[mt], wh[nt],  z2a[mt][nt], 0, 0, 0);
                z2a[mt][nt] = __builtin_amdgcn_mfma_f32_16x16x32_bf16(al2[mt], wh[nt],  z2a[mt][nt], 0, 0, 0);
                z2a[mt][nt] = __builtin_amdgcn_mfma_f32_16x16x32_bf16(ah2[mt], wl2[nt], z2a[mt][nt], 0, 0, 0);
            }
        #pragma unroll
        for (int mt = 0; mt < 4; ++mt) {
            bf16x8 mh = maskand(ah2[mt], wlh);
            #pragma unroll
            for (int nt = 0; nt < 4; ++nt) {
                z2m[mt][nt] = __builtin_amdgcn_mfma_f32_16x16x32_bf16(mh, wh[nt],  z2m[mt][nt], 0, 0, 0);
                z2m[mt][nt] = __builtin_amdgcn_mfma_f32_16x16x32_bf16(mh, wl2[nt], z2m[mt][nt], 0, 0, 0);
            }
            bf16x8 ml = maskand(ah2[mt], wll);
            #pragma unroll
            for (int nt = 0; nt < 4; ++nt)
                z2m[mt][nt] = __builtin_amdgcn_mfma_f32_16x16x32_bf16(ml, wh[nt], z2m[mt][nt], 0, 0, 0);
        }
    }

    // ---- epilogue: per-row dot with w3, via wave-private LDS transpose ----
    float b2c[4], w3c[4], rsv[4];
    #pragma unroll
    for (int nt = 0; nt < 4; ++nt) {
        int g = nt * 16 + c16;
        b2c[nt] = b2[l * 64 + g];
        w3c[nt] = W3[l * 64 + g];
        rsv[nt] = RSV[l * 64 + g];
    }
    float* spo = (float*)a1h + wid * 2176;   // wave's own quarter (2176 floats)
    float* spd = (float*)a1l + wid * 2176;
    #pragma unroll
    for (int mt = 0; mt < 4; ++mt)
        #pragma unroll
        for (int r = 0; r < 4; ++r) {
            float po = 0.f, pd = 0.f;
            #pragma unroll
            for (int nt = 0; nt < 4; ++nt) {
                float z  = z2a[mt][nt][r] + b2c[nt];
                float a2 = z > 0.f ? z : 0.01f * z;
                float d2 = z > 0.f ? 1.0f : 0.01f;
                float zt = 0.01f * rsv[nt] + 0.99f * z2m[mt][nt][r];
                po += a2 * w3c[nt];
                pd += d2 * zt * w3c[nt];
            }
            int row = mt * 16 + q * 4 + r;   // 0..63
            spo[row * 17 + c16] = po;
            spd[row * 17 + c16] = pd;
        }
    __threadfence_block();

    {
        float so = 0.f, sd = 0.f;
        #pragma unroll
        for (int j = 0; j < 16; ++j) {
            so += spo[lane * 17 + j];
            sd += spd[lane * 17 + j];
        }
        int n = nb + wrow + lane;
        out[(size_t)n * 64 + l] = so + b3[l];
        PD[(size_t)l * NTOT + n] = sd;       // coalesced; log+sum in finish kernel
    }
}

extern "C" void kernel_launch(void* const* d_in, const int* in_sizes, int n_in,
                              void* d_out, int out_size, void* d_ws, size_t ws_size,
                              hipStream_t stream) {
    const float* x  = (const float*)d_in[0];
    const float* W1 = (const float*)d_in[1];
    const float* b1 = (const float*)d_in[2];
    const float* W2 = (const float*)d_in[3];
    const float* b2 = (const float*)d_in[4];
    const float* W3 = (const float*)d_in[5];
    const float* b3 = (const float*)d_in[6];
    float* out = (float*)d_out;
    char* ws = (char*)d_ws;

    short* XH   = (short*)(ws + OXH);
    short* XL   = (short*)(ws + OXL);
    short* W1Hp = (short*)(ws + OW1H);
    short* W1Lp = (short*)(ws + OW1L);
    short* W2Hp = (short*)(ws + OW2H);
    short* W2Lp = (short*)(ws + OW2L);
    short* WLHp = (short*)(ws + OWLH);
    short* WLLp = (short*)(ws + OWLL);
    float* RSVp = (float*)(ws + ORSV);
    float* PDp  = (float*)(ws + OPD);

    hipLaunchKernelGGL(prep_all, dim3(1026 + 384 + 64), dim3(256), 0, stream,
                       x, W1, W2, XH, XL, W1Hp, W1Lp, W2Hp, W2Lp, WLHp, WLLp, RSVp);
    dim3 grid(64 /*l*/, NTOT / 256 /*n tiles of 256*/);
    hipLaunchKernelGGL(np_main, grid, dim3(256), 0, stream,
                       x, W1, b1, b2, W3, b3,
                       XH, XL, W1Hp, W1Lp, W2Hp, W2Lp, WLHp, WLLp, RSVp, PDp, out);
    hipLaunchKernelGGL(finish_logdet, dim3(NTOT / 256), dim3(256), 0, stream,
                       PDp, out + (size_t)NTOT * 64);
}